// Round 1
// baseline (2153.151 us; speedup 1.0000x reference)
//
#include <hip/hip_runtime.h>
#include <hip/hip_bf16.h>

// GraphConv x2:  h = relu(seg_sum(x[src]*w, dst) @ Wrel1^T + b1 + x @ Wroot1^T)
//                out =     seg_sum(h[src]*w, dst) @ Wrel2^T + b2 + h @ Wroot2^T
// N=100000, E=1600000, D=64

#define D 64

// ---------------- scatter-add: agg[dst] += x[src] * w ----------------
// one thread per (edge, feature-pair): t&31 selects which float2 of the row,
// t>>5 selects the edge. 32 threads/edge -> 256B contiguous gather per edge.
__global__ __launch_bounds__(256) void scatter_kernel(
    const float* __restrict__ x, const int* __restrict__ ei,
    const float* __restrict__ ew, float* __restrict__ agg, int E_)
{
    int t = blockIdx.x * blockDim.x + threadIdx.x;
    int e = t >> 5;
    if (e >= E_) return;
    int p = (t & 31) * 2;           // feature pair start
    int src = ei[e];
    int dst = ei[E_ + e];
    float w = ew[e];
    const float2 v = *reinterpret_cast<const float2*>(&x[src * D + p]);
    atomicAdd(&agg[dst * D + p],     v.x * w);
    atomicAdd(&agg[dst * D + p + 1], v.y * w);
}

// ---------------- fused linear: out = agg@Wrel^T + b + xin@Wroot^T ----------------
// one wave per row; W matrices staged transposed in LDS so lane-d reads are
// bank-conflict-free (consecutive addresses); row broadcast from LDS.
#define NWAVES 4
template <bool RELU>
__global__ __launch_bounds__(256) void linear_kernel(
    const float* __restrict__ agg, const float* __restrict__ xin,
    const float* __restrict__ Wrel, const float* __restrict__ brel,
    const float* __restrict__ Wroot, float* __restrict__ out, int Nn)
{
    __shared__ float WrelT[D * D];   // WrelT[k*64+d] = Wrel[d*64+k]
    __shared__ float WrootT[D * D];
    __shared__ float bias[D];
    __shared__ float rowA[NWAVES][D];
    __shared__ float rowX[NWAVES][D];

    int tid = threadIdx.x;
    for (int i = tid; i < D * D; i += 256) {
        int d = i >> 6, k = i & 63;
        WrelT[k * D + d]  = Wrel[i];
        WrootT[k * D + d] = Wroot[i];
    }
    if (tid < D) bias[tid] = brel[tid];
    __syncthreads();

    int wave = tid >> 6, lane = tid & 63;

    for (int i = blockIdx.x * NWAVES + wave; i < Nn; i += gridDim.x * NWAVES) {
        rowA[wave][lane] = agg[i * D + lane];
        rowX[wave][lane] = xin[i * D + lane];
        // same-wave LDS write->read: compiler inserts lgkmcnt wait; no barrier needed
        float acc = bias[lane];
#pragma unroll 8
        for (int k = 0; k < D; ++k) {
            acc += rowA[wave][k] * WrelT[k * D + lane];
            acc += rowX[wave][k] * WrootT[k * D + lane];
        }
        out[i * D + lane] = RELU ? fmaxf(acc, 0.f) : acc;
    }
}

extern "C" void kernel_launch(void* const* d_in, const int* in_sizes, int n_in,
                              void* d_out, int out_size, void* d_ws, size_t ws_size,
                              hipStream_t stream)
{
    const float* x      = (const float*)d_in[0];
    const int*   ei     = (const int*)  d_in[1];   // [2, E] int32 (JAX x64 off)
    const float* ew     = (const float*)d_in[2];
    const float* Wrel1  = (const float*)d_in[3];
    const float* brel1  = (const float*)d_in[4];
    const float* Wroot1 = (const float*)d_in[5];
    const float* Wrel2  = (const float*)d_in[6];
    const float* brel2  = (const float*)d_in[7];
    const float* Wroot2 = (const float*)d_in[8];
    float* out = (float*)d_out;

    const int E_ = in_sizes[2];          // 1600000
    const int Nn = in_sizes[0] / D;      // 100000

    float* agg = (float*)d_ws;                      // [N, D]
    float* h   = (float*)d_ws + (size_t)Nn * D;     // [N, D]

    const size_t aggBytes = (size_t)Nn * D * sizeof(float);
    const int scatterBlocks = (E_ * 32 + 255) / 256;
    const int linearBlocks  = (Nn + NWAVES - 1) / NWAVES;

    // ---- layer 1 ----
    hipMemsetAsync(agg, 0, aggBytes, stream);
    scatter_kernel<<<scatterBlocks, 256, 0, stream>>>(x, ei, ew, agg, E_);
    linear_kernel<true><<<linearBlocks, 256, 0, stream>>>(agg, x, Wrel1, brel1, Wroot1, h, Nn);

    // ---- layer 2 ----
    hipMemsetAsync(agg, 0, aggBytes, stream);
    scatter_kernel<<<scatterBlocks, 256, 0, stream>>>(h, ei, ew, agg, E_);
    linear_kernel<false><<<linearBlocks, 256, 0, stream>>>(agg, h, Wrel2, brel2, Wroot2, out, Nn);
}

// Round 2
// 502.512 us; speedup vs baseline: 4.2848x; 4.2848x over previous
//
#include <hip/hip_runtime.h>
#include <hip/hip_bf16.h>

// GraphConv x2 via CSR-gather (no f32 atomics):
//   CSR by dst built once (hist -> scan -> fill), reused for both layers.
//   fused_layer: per node i (one wave, lane=feature):
//     acc = sum_j x[src_j]*w_j  (register gather)
//     out[i] = acc @ Wrel^T + b + x[i] @ Wroot^T  (LDS weights), opt ReLU
// N=100000, E=1600000, D=64

#define D 64
#define NW 8            // waves (nodes) per block, block = 512 threads
#define SCAN_CHUNK 1024

// ---------------- CSR build ----------------
__global__ __launch_bounds__(256) void hist_kernel(
    const int* __restrict__ ei, int* __restrict__ deg, int E_)
{
    int e = blockIdx.x * 256 + threadIdx.x;
    if (e >= E_) return;
    atomicAdd(&deg[ei[E_ + e]], 1);
}

// per-chunk local exclusive scan (1024 elems / block of 256 thr x 4) + chunk total
__global__ __launch_bounds__(256) void scan1_kernel(
    const int* __restrict__ deg, int* __restrict__ loc, int* __restrict__ partial, int n)
{
    __shared__ int wsum[4];
    int t = threadIdx.x;
    int base = blockIdx.x * SCAN_CHUNK + t * 4;
    int v0 = (base + 0 < n) ? deg[base + 0] : 0;
    int v1 = (base + 1 < n) ? deg[base + 1] : 0;
    int v2 = (base + 2 < n) ? deg[base + 2] : 0;
    int v3 = (base + 3 < n) ? deg[base + 3] : 0;
    int s = v0 + v1 + v2 + v3;
    int lane = t & 63, wave = t >> 6;
    int inc = s;
    for (int off = 1; off < 64; off <<= 1) {
        int u = __shfl_up(inc, off);
        if (lane >= off) inc += u;
    }
    if (lane == 63) wsum[wave] = inc;
    __syncthreads();
    int woff = 0;
    for (int w = 0; w < wave; ++w) woff += wsum[w];
    int ex = woff + inc - s;   // exclusive prefix of this thread's 4-group
    if (base + 0 < n) loc[base + 0] = ex;
    if (base + 1 < n) loc[base + 1] = ex + v0;
    if (base + 2 < n) loc[base + 2] = ex + v0 + v1;
    if (base + 3 < n) loc[base + 3] = ex + v0 + v1 + v2;
    if (t == 255) partial[blockIdx.x] = woff + inc;  // chunk total
}

// exclusive scan of chunk totals (nchunk <= 1024), single block
__global__ __launch_bounds__(1024) void scan2_kernel(int* __restrict__ partial, int nchunk)
{
    __shared__ int sd[1024];
    int t = threadIdx.x;
    if (t < nchunk) sd[t] = partial[t];
    __syncthreads();
    if (t == 0) {
        int run = 0;
        for (int i = 0; i < nchunk; ++i) { int v = sd[i]; sd[i] = run; run += v; }
    }
    __syncthreads();
    if (t < nchunk) partial[t] = sd[t];
}

// rowptr[i] = loc[i] + partial[chunk]; cursor copy; rowptr[n] = E
__global__ __launch_bounds__(256) void scan3_kernel(
    int* __restrict__ rowptr, const int* __restrict__ partial,
    int* __restrict__ cursor, int n, int Etot)
{
    int i = blockIdx.x * 256 + threadIdx.x;
    if (i == 0) rowptr[n] = Etot;
    if (i >= n) return;
    int v = rowptr[i] + partial[i >> 10];
    rowptr[i] = v;
    cursor[i] = v;
}

__global__ __launch_bounds__(256) void fill_kernel(
    const int* __restrict__ ei, const float* __restrict__ ew,
    int* __restrict__ cursor, float2* __restrict__ pairs, int E_)
{
    int e = blockIdx.x * 256 + threadIdx.x;
    if (e >= E_) return;
    int src = ei[e];
    int dst = ei[E_ + e];
    int p = atomicAdd(&cursor[dst], 1);
    pairs[p] = make_float2(__int_as_float(src), ew[e]);
}

// ---------------- fused layer ----------------
template <bool RELU>
__global__ __launch_bounds__(512) void fused_layer(
    const float* __restrict__ xin, const float2* __restrict__ pairs,
    const int* __restrict__ rowptr,
    const float* __restrict__ Wrel, const float* __restrict__ brel,
    const float* __restrict__ Wroot, float* __restrict__ out, int Nn)
{
    __shared__ float WrelT[D * D];   // WrelT[k*64+d] = Wrel[d*64+k], lane-d reads conflict-free
    __shared__ float WrootT[D * D];
    __shared__ float bias[D];
    __shared__ float rowA[NW][D];
    __shared__ float rowX[NW][D];

    int tid = threadIdx.x;
    for (int i = tid; i < D * D; i += 512) {
        int d = i >> 6, k = i & 63;
        WrelT[k * D + d]  = Wrel[i];
        WrootT[k * D + d] = Wroot[i];
    }
    if (tid < D) bias[tid] = brel[tid];
    __syncthreads();

    int wave = tid >> 6, lane = tid & 63;

    for (int i = blockIdx.x * NW + wave; i < Nn; i += gridDim.x * NW) {
        int beg = rowptr[i], end = rowptr[i + 1];
        float acc = 0.f;
        for (int b = beg; b < end; b += 64) {
            int cnt = min(64, end - b);
            float2 pr = (lane < cnt) ? pairs[b + lane] : make_float2(0.f, 0.f);
            int   ps = __float_as_int(pr.x);
            int j = 0;
            for (; j + 4 <= cnt; j += 4) {           // 4-deep MLP on the gather
                int   s0 = __shfl(ps, j),     s1 = __shfl(ps, j + 1);
                int   s2 = __shfl(ps, j + 2), s3 = __shfl(ps, j + 3);
                float w0 = __shfl(pr.y, j),     w1 = __shfl(pr.y, j + 1);
                float w2 = __shfl(pr.y, j + 2), w3 = __shfl(pr.y, j + 3);
                float v0 = xin[(size_t)s0 * D + lane];
                float v1 = xin[(size_t)s1 * D + lane];
                float v2 = xin[(size_t)s2 * D + lane];
                float v3 = xin[(size_t)s3 * D + lane];
                acc += v0 * w0; acc += v1 * w1; acc += v2 * w2; acc += v3 * w3;
            }
            for (; j < cnt; ++j) {
                int s = __shfl(ps, j);
                float w = __shfl(pr.y, j);
                acc += xin[(size_t)s * D + lane] * w;
            }
        }

        rowA[wave][lane] = acc;
        rowX[wave][lane] = xin[(size_t)i * D + lane];
        // same-wave LDS write->read: compiler inserts lgkmcnt wait

        const float4* rA4 = reinterpret_cast<const float4*>(rowA[wave]);
        const float4* rX4 = reinterpret_cast<const float4*>(rowX[wave]);
        float o = bias[lane];
#pragma unroll
        for (int k4 = 0; k4 < 16; ++k4) {
            float4 a = rA4[k4];       // broadcast b128
            float4 xr = rX4[k4];
            int k = k4 * 4;
            o += a.x  * WrelT[(k + 0) * D + lane];
            o += a.y  * WrelT[(k + 1) * D + lane];
            o += a.z  * WrelT[(k + 2) * D + lane];
            o += a.w  * WrelT[(k + 3) * D + lane];
            o += xr.x * WrootT[(k + 0) * D + lane];
            o += xr.y * WrootT[(k + 1) * D + lane];
            o += xr.z * WrootT[(k + 2) * D + lane];
            o += xr.w * WrootT[(k + 3) * D + lane];
        }
        out[(size_t)i * D + lane] = RELU ? fmaxf(o, 0.f) : o;
    }
}

extern "C" void kernel_launch(void* const* d_in, const int* in_sizes, int n_in,
                              void* d_out, int out_size, void* d_ws, size_t ws_size,
                              hipStream_t stream)
{
    const float* x      = (const float*)d_in[0];
    const int*   ei     = (const int*)  d_in[1];   // [2, E] int32
    const float* ew     = (const float*)d_in[2];
    const float* Wrel1  = (const float*)d_in[3];
    const float* brel1  = (const float*)d_in[4];
    const float* Wroot1 = (const float*)d_in[5];
    const float* Wrel2  = (const float*)d_in[6];
    const float* brel2  = (const float*)d_in[7];
    const float* Wroot2 = (const float*)d_in[8];
    float* out = (float*)d_out;

    const int E_ = in_sizes[2];          // 1600000
    const int Nn = in_sizes[0] / D;      // 100000

    // workspace layout
    char* w = (char*)d_ws;
    size_t off = 0;
    float* h      = (float*)(w + off); off += (size_t)Nn * D * sizeof(float);
    int*   rowptr = (int*)  (w + off); off += (size_t)(Nn + 1) * sizeof(int);
    int*   cursor = (int*)  (w + off); off += (size_t)Nn * sizeof(int);
    int*   partial= (int*)  (w + off); off += 1024 * sizeof(int);
    off = (off + 15) & ~(size_t)15;
    float2* pairs = (float2*)(w + off);

    const int nchunk = (Nn + SCAN_CHUNK - 1) / SCAN_CHUNK;
    const int eBlocks = (E_ + 255) / 256;

    // ---- CSR build (once, reused by both layers) ----
    hipMemsetAsync(cursor, 0, (size_t)Nn * sizeof(int), stream);   // deg counts
    hist_kernel<<<eBlocks, 256, 0, stream>>>(ei, cursor, E_);
    scan1_kernel<<<nchunk, 256, 0, stream>>>(cursor, rowptr, partial, Nn);
    scan2_kernel<<<1, 1024, 0, stream>>>(partial, nchunk);
    scan3_kernel<<<(Nn + 255) / 256, 256, 0, stream>>>(rowptr, partial, cursor, Nn, E_);
    fill_kernel<<<eBlocks, 256, 0, stream>>>(ei, ew, cursor, pairs, E_);

    // ---- fused layers ----
    const int fGrid = 1024;   // 4 blocks/CU (LDS ~36KB) x 256 CU, grid-stride
    fused_layer<true ><<<fGrid, 512, 0, stream>>>(x, pairs, rowptr, Wrel1, brel1, Wroot1, h, Nn);
    fused_layer<false><<<fGrid, 512, 0, stream>>>(h, pairs, rowptr, Wrel2, brel2, Wroot2, out, Nn);
}